// Round 14
// baseline (142.822 us; speedup 1.0000x reference)
//
#include <hip/hip_runtime.h>

// B=2, SQ=SKV=2048, D=1024, H=16, HD=64. Inputs fp32, output fp32.
// r13: 129us; reg-staged fp32 proj staging broke the async pipeline (35->70us).
// r14: (1) proj reverted to r11 path (cvt_all inputs+weights, all gload_lds);
// (2) attn mf=4 (64 q/wave): halves per-work LDS traffic (was 4x LDS-BW-bound),
// 256 blocks, LDS 100KB/block, launch_bounds(256,1).
#define DIM   1024
#define NHEAD 16
#define HDIM  64
#define BATCH 2
#define SEQ   2048
#define MTOT  4096   // B*SQ

typedef unsigned short u16;
typedef unsigned int   u32;
typedef __attribute__((ext_vector_type(8))) short bf16x8;   // 8 bf16 = 4 VGPRs
typedef __attribute__((ext_vector_type(4))) float f32x4;
typedef __attribute__((ext_vector_type(2))) u32   u32x2;
typedef __attribute__((ext_vector_type(4))) u32   u32x4;

#define QSCALE 0.18033688011112042f   // 0.125 * log2(e)
#define EXP2F(x) __builtin_amdgcn_exp2f(x)

__device__ __forceinline__ void gload_lds16(const void* g, void* l) {
  __builtin_amdgcn_global_load_lds((const __attribute__((address_space(1))) void*)g,
                                   (__attribute__((address_space(3))) void*)l, 16, 0, 0);
}

__device__ __forceinline__ u16 f32_to_bf16(float f) {
  union { float f; u32 u; } v; v.f = f;
  u32 r = v.u + 0x7fffu + ((v.u >> 16) & 1u);   // RNE (v_cvt_pk_bf16_f32 is NOT RNE - r12)
  return (u16)(r >> 16);
}

__device__ __forceinline__ u32 pack_bf16(float a, float b) {
  return (u32)f32_to_bf16(a) | ((u32)f32_to_bf16(b) << 16);
}

// ---------------------------------------------------------------------------
// fp32 -> bf16 for all 7 tensors (3 inputs + 4 weights), manual RNE.
// ---------------------------------------------------------------------------
struct CvtArgs {
  const float* s[7];
  u16*         d[7];
  int          n8[7];
};

__global__ __launch_bounds__(256) void cvt_all(CvtArgs a) {
  const int z = blockIdx.z;
  const float* s = a.s[z];
  u16* d = a.d[z];
  const int n8 = a.n8[z];
  const int stride = gridDim.x * blockDim.x;
  for (int i = blockIdx.x * blockDim.x + threadIdx.x; i < n8; i += stride) {
    float4 x = ((const float4*)s)[2 * i], y = ((const float4*)s)[2 * i + 1];
    u32x4 o;
    o[0] = pack_bf16(x.x, x.y); o[1] = pack_bf16(x.z, x.w);
    o[2] = pack_bf16(y.x, y.y); o[3] = pack_bf16(y.z, y.w);
    *(u32x4*)&d[(size_t)i * 8] = o;
  }
}

// ---------------------------------------------------------------------------
// bf16 GEMM body (r11-proven): tile (32*MF) x 128, BK=64, 4 waves (2x2),
// all-gload_lds staging + both-sides XOR swizzle.
// ---------------------------------------------------------------------------
template<int MF, bool OUTF32, bool BIAS_ROW>
__device__ __forceinline__ void gemm_body(
    const u16* __restrict__ X, const u16* __restrict__ W,
    const float* __restrict__ bias, void* __restrict__ Cv, int ldc, float scale,
    int m0, int n0)
{
  __shared__ __align__(16) u16 ldsA[32 * 4 * 64];
  __shared__ __align__(16) u16 ldsB[128 * 64];
  const int tid  = threadIdx.x;
  const int lane = tid & 63;
  const int wid  = tid >> 6;
  const int wr   = wid >> 1, wc = wid & 1;
  const int srow = tid >> 3;
  const int scs  = tid & 7;

  f32x4 acc[MF][4];
#pragma unroll
  for (int mf = 0; mf < MF; ++mf)
#pragma unroll
    for (int nf = 0; nf < 4; ++nf)
#pragma unroll
      for (int r = 0; r < 4; ++r) acc[mf][nf][r] = 0.f;

  for (int kt = 0; kt < DIM; kt += 64) {
    __syncthreads();
#pragma unroll
    for (int call = 0; call < MF; ++call) {
      int row = call * 32 + srow;
      int lc  = scs ^ (row & 7);
      gload_lds16(X + (size_t)(m0 + row) * DIM + kt + lc * 8,
                  &ldsA[(row * 8 + scs) * 8]);
    }
#pragma unroll
    for (int call = 0; call < 4; ++call) {
      int row = call * 32 + srow;
      int lc  = scs ^ (row & 7);
      gload_lds16(W + (size_t)(n0 + row) * DIM + kt + lc * 8,
                  &ldsB[(row * 8 + scs) * 8]);
    }
    __syncthreads();
#pragma unroll
    for (int ks = 0; ks < 2; ++ks) {
      bf16x8 af[MF], bfr[4];
#pragma unroll
      for (int mf = 0; mf < MF; ++mf) {
        int row = wr * (16 * MF) + mf * 16 + (lane & 15);
        int ch  = (ks * 4 + (lane >> 4)) ^ (row & 7);
        af[mf] = *(const bf16x8*)&ldsA[row * 64 + ch * 8];
      }
#pragma unroll
      for (int nf = 0; nf < 4; ++nf) {
        int row = wc * 64 + nf * 16 + (lane & 15);
        int ch  = (ks * 4 + (lane >> 4)) ^ (row & 7);
        bfr[nf] = *(const bf16x8*)&ldsB[row * 64 + ch * 8];
      }
#pragma unroll
      for (int mf = 0; mf < MF; ++mf)
#pragma unroll
        for (int nf = 0; nf < 4; ++nf)
          acc[mf][nf] = __builtin_amdgcn_mfma_f32_16x16x32_bf16(
              af[mf], bfr[nf], acc[mf][nf], 0, 0, 0);
    }
  }
#pragma unroll
  for (int nf = 0; nf < 4; ++nf) {
    int col = n0 + wc * 64 + nf * 16 + (lane & 15);
    float bcol = BIAS_ROW ? 0.f : bias[col];
#pragma unroll
    for (int mf = 0; mf < MF; ++mf) {
      int rbase = m0 + wr * (16 * MF) + mf * 16 + ((lane >> 4) << 2);
#pragma unroll
      for (int r = 0; r < 4; ++r) {
        float bv = BIAS_ROW ? bias[rbase + r] : bcol;
        float v = (acc[mf][nf][r] + bv) * scale;
        if (OUTF32) ((float*)Cv)[(size_t)(rbase + r) * ldc + col] = v;
        else        ((u16*)Cv)[(size_t)(rbase + r) * ldc + col] = f32_to_bf16(v);
      }
    }
  }
}

// Fused projections, 1D grid 768, XCD-chunked: z=0 Q, z=1 K, z=2 V^T.
__global__ __launch_bounds__(256, 2) void gemm_proj_kernel(
    const u16* __restrict__ q, const u16* __restrict__ k, const u16* __restrict__ v,
    const u16* __restrict__ wq, const u16* __restrict__ wk, const u16* __restrict__ wv,
    const float* __restrict__ bq, const float* __restrict__ bk, const float* __restrict__ bv,
    u16* __restrict__ oq, u16* __restrict__ ok, u16* __restrict__ ovt)
{
  const int bid = blockIdx.x;
  const int wk_ = (bid & 7) * 96 + (bid >> 3);   // 768 = 8 XCD x 96, bijective
  const int z = wk_ >> 8, rem = wk_ & 255;
  const int ty = rem >> 3, tx = rem & 7;
  if (z == 0)
    gemm_body<4, false, false>(q, wq, bq, oq, DIM, QSCALE, ty * 128, tx * 128);
  else if (z == 1)
    gemm_body<4, false, false>(k, wk, bk, ok, DIM, 1.0f, ty * 128, tx * 128);
  else
    gemm_body<4, false, true>(wv, v, bv, ovt, MTOT, 1.0f, tx * 128, ty * 128);
}

// O projection: 64x128 tile, 1D grid 512, XCD-chunked.
__global__ __launch_bounds__(256, 2) void gemm_o_kernel(
    const u16* __restrict__ x, const u16* __restrict__ w,
    const float* __restrict__ b, float* __restrict__ c)
{
  const int bid = blockIdx.x;
  const int wk_ = (bid & 7) * 64 + (bid >> 3);   // 512 = 8 x 64, bijective
  const int ty = wk_ >> 3, tx = wk_ & 7;
  gemm_body<2, true, false>(x, w, b, c, DIM, 1.0f, ty * 64, tx * 128);
}

// ---------------------------------------------------------------------------
// Flash attention r14: 4 waves x 64 q-rows (mf=4), 256 blocks (1/CU).
// Halves LDS traffic per unit MFMA vs r13 (was 4x LDS-BW-bound).
// Swapped QK^T, no-max exp2 softmax, ones-column ell, dbuf+counted-vmcnt.
// LDS: K/V dbuf 64KB + P 36KB = 100KB (fits 160KB, 1 block/CU).
// ---------------------------------------------------------------------------
#define PSTR 72

__global__ __launch_bounds__(256, 1) void attn_kernel(
    const u16* __restrict__ Qm, const u16* __restrict__ Km,
    const u16* __restrict__ Vt, u16* __restrict__ Cm)
{
  __shared__ __align__(16) u16 Kl[2][64 * 64];
  __shared__ __align__(16) u16 Vl[2][64 * 64];
  __shared__ __align__(16) u16 Pl[4][64 * PSTR];

  const int tid = threadIdx.x, lane = tid & 63, wid = tid >> 6;
  const int c = lane & 15, g = lane >> 4;
  const int wkid = (blockIdx.x & 7) * 32 + (blockIdx.x >> 3);   // 256 = 8 x 32
  const int qt = wkid & 7;            // 8 q-tiles of 256 rows
  const int bh = wkid >> 3;           // 32 (b,h); 4 consecutive per XCD
  const int b = bh >> 4, h = bh & 15;
  const size_t hb = (size_t)h * HDIM;
  const int q0 = qt * 256 + wid * 64;            // wave's first q row
  const u16* Qh = Qm + ((size_t)b * SEQ + q0) * DIM + hb;
  const u16* Kh = Km + (size_t)b * SEQ * DIM + hb;
  const u16* Vh = Vt + (size_t)(h * HDIM) * MTOT + (size_t)b * SEQ;

  // Q B-frags: col q = 16mf + c, k = 32ks + 8g + j
  bf16x8 qf[4][2];
#pragma unroll
  for (int mf = 0; mf < 4; ++mf)
#pragma unroll
    for (int ks = 0; ks < 2; ++ks)
      qf[mf][ks] = *(const bf16x8*)(Qh + (size_t)(16 * mf + c) * DIM + ks * 32 + g * 8);

  bf16x8 ones;
#pragma unroll
  for (int j = 0; j < 8; ++j) ((short*)&ones)[j] = (short)0x3F80;   // bf16 1.0

  f32x4 oacc[4][4], lacc[4];
#pragma unroll
  for (int mf = 0; mf < 4; ++mf) {
#pragma unroll
    for (int nd = 0; nd < 4; ++nd)
#pragma unroll
      for (int r = 0; r < 4; ++r) oacc[mf][nd][r] = 0.f;
#pragma unroll
    for (int r = 0; r < 4; ++r) lacc[mf][r] = 0.f;
  }

  const int srow = tid >> 3, scs = tid & 7;
  u16* pw = &Pl[wid][0];

#define STAGE(T, BUF)                                                          \
  {                                                                            \
    const int kvs = (T) * 64;                                                  \
    _Pragma("unroll")                                                          \
    for (int call = 0; call < 2; ++call) {                                     \
      int row = call * 32 + srow;                                              \
      int lc  = scs ^ (row & 7);                                               \
      gload_lds16(Kh + (size_t)(kvs + row) * DIM + lc * 8,                     \
                  &Kl[BUF][(row * 8 + scs) * 8]);                              \
      gload_lds16(Vh + (size_t)row * MTOT + kvs + lc * 8,                      \
                  &Vl[BUF][(row * 8 + scs) * 8]);                              \
    }                                                                          \
  }

  STAGE(0, 0);

  for (int t = 0; t < 32; ++t) {
    const int cur = t & 1;
    if (t < 31) {
      STAGE(t + 1, cur ^ 1);
      asm volatile("s_waitcnt vmcnt(4)" ::: "memory");
    } else {
      asm volatile("s_waitcnt vmcnt(0)" ::: "memory");
    }
    __builtin_amdgcn_sched_barrier(0);
    __builtin_amdgcn_s_barrier();          // buf[cur] staged & visible
    __builtin_amdgcn_sched_barrier(0);

    // ---- QK^T swapped: sacc[nvk][mf] = K-tile x Q, D[kv][q] ----
    f32x4 sacc[4][4];
#pragma unroll
    for (int nvk = 0; nvk < 4; ++nvk)
#pragma unroll
      for (int mf = 0; mf < 4; ++mf)
#pragma unroll
        for (int r = 0; r < 4; ++r) sacc[nvk][mf][r] = 0.f;
#pragma unroll
    for (int ks = 0; ks < 2; ++ks) {
      bf16x8 kf[4];
#pragma unroll
      for (int nvk = 0; nvk < 4; ++nvk) {
        int row = nvk * 16 + c;            // kv row
        int ch  = (ks * 4 + g) ^ (row & 7);
        kf[nvk] = *(const bf16x8*)&Kl[cur][row * 64 + ch * 8];
      }
#pragma unroll
      for (int nvk = 0; nvk < 4; ++nvk)
#pragma unroll
        for (int mf = 0; mf < 4; ++mf)
          sacc[nvk][mf] = __builtin_amdgcn_mfma_f32_16x16x32_bf16(
              kf[nvk], qf[mf][ks], sacc[nvk][mf], 0, 0, 0);
    }

    // ---- p = exp2(s), packed manual-RNE b64: P[q=16mf+c][kv=16nvk+4g+r] ----
#pragma unroll
    for (int nvk = 0; nvk < 4; ++nvk)
#pragma unroll
      for (int mf = 0; mf < 4; ++mf) {
        u32x2 pk2;
        pk2[0] = pack_bf16(EXP2F(sacc[nvk][mf][0]), EXP2F(sacc[nvk][mf][1]));
        pk2[1] = pack_bf16(EXP2F(sacc[nvk][mf][2]), EXP2F(sacc[nvk][mf][3]));
        *(u32x2*)&pw[(16 * mf + c) * PSTR + 16 * nvk + 4 * g] = pk2;
      }

    // ---- PV + ones-ell ----
#pragma unroll
    for (int ks = 0; ks < 2; ++ks) {
      bf16x8 pf[4];
#pragma unroll
      for (int mf = 0; mf < 4; ++mf)
        pf[mf] = *(const bf16x8*)&pw[(16 * mf + c) * PSTR + ks * 32 + g * 8];
#pragma unroll
      for (int mf = 0; mf < 4; ++mf)
        lacc[mf] = __builtin_amdgcn_mfma_f32_16x16x32_bf16(
            pf[mf], ones, lacc[mf], 0, 0, 0);
#pragma unroll
      for (int nd = 0; nd < 4; ++nd) {
        int row = nd * 16 + c;             // d row of V^T tile
        int ch  = (ks * 4 + g) ^ (row & 7);
        bf16x8 vfr = *(const bf16x8*)&Vl[cur][row * 64 + ch * 8];
#pragma unroll
        for (int mf = 0; mf < 4; ++mf)
          oacc[mf][nd] = __builtin_amdgcn_mfma_f32_16x16x32_bf16(
              pf[mf], vfr, oacc[mf][nd], 0, 0, 0);
      }
    }

    __builtin_amdgcn_sched_barrier(0);
    __builtin_amdgcn_s_barrier();          // all waves done with buf[cur]
  }
#undef STAGE

  // epilogue: q = q0 + 16mf + 4g + r, d = 16nd + c
#pragma unroll
  for (int mf = 0; mf < 4; ++mf)
#pragma unroll
    for (int nd = 0; nd < 4; ++nd)
#pragma unroll
      for (int r = 0; r < 4; ++r) {
        int q = q0 + 16 * mf + 4 * g + r;
        float v = oacc[mf][nd][r] / lacc[mf][r];
        Cm[((size_t)b * SEQ + q) * DIM + hb + nd * 16 + c] = f32_to_bf16(v);
      }
}

// ---------------------------------------------------------------------------
extern "C" void kernel_launch(void* const* d_in, const int* in_sizes, int n_in,
                              void* d_out, int out_size, void* d_ws, size_t ws_size,
                              hipStream_t stream)
{
  const float* query = (const float*)d_in[0];
  const float* key   = (const float*)d_in[1];
  const float* value = (const float*)d_in[2];
  const float* Wq = (const float*)d_in[3];  const float* bq = (const float*)d_in[4];
  const float* Wk = (const float*)d_in[5];  const float* bk = (const float*)d_in[6];
  const float* Wv = (const float*)d_in[7];  const float* bv = (const float*)d_in[8];
  const float* Wo = (const float*)d_in[9];  const float* bo = (const float*)d_in[10];
  float* out = (float*)d_out;

  const size_t NQKV = (size_t)MTOT * DIM;
  const size_t NW   = (size_t)DIM * DIM;
  u16* base = (u16*)d_ws;
  u16* Qb  = base;                 // [4096,1024] (pre-scaled by QSCALE)
  u16* Kb  = Qb + NQKV;
  u16* Vtb = Kb + NQKV;            // [1024,4096] V^T
  u16* Cb  = Vtb + NQKV;
  u16* qc  = Cb + NQKV;
  u16* kc  = qc + NQKV;
  u16* vc  = kc + NQKV;
  u16* wqc = vc + NQKV;
  u16* wkc = wqc + NW;
  u16* wvc = wkc + NW;
  u16* woc = wvc + NW;

  CvtArgs ca;
  ca.s[0] = query; ca.s[1] = key; ca.s[2] = value;
  ca.s[3] = Wq; ca.s[4] = Wk; ca.s[5] = Wv; ca.s[6] = Wo;
  ca.d[0] = qc; ca.d[1] = kc; ca.d[2] = vc;
  ca.d[3] = wqc; ca.d[4] = wkc; ca.d[5] = wvc; ca.d[6] = woc;
  for (int i = 0; i < 3; ++i) ca.n8[i] = (int)(NQKV / 8);
  for (int i = 3; i < 7; ++i) ca.n8[i] = (int)(NW / 8);
  cvt_all<<<dim3(256, 1, 7), 256, 0, stream>>>(ca);

  dim3 blk(256);
  gemm_proj_kernel<<<768, blk, 0, stream>>>(
      qc, kc, vc, wqc, wkc, wvc, bq, bk, bv, Qb, Kb, Vtb);
  attn_kernel<<<256, blk, 0, stream>>>(Qb, Kb, Vtb, Cb);
  gemm_o_kernel<<<512, blk, 0, stream>>>(Cb, woc, bo, out);
}

// Round 15
// 125.554 us; speedup vs baseline: 1.1375x; 1.1375x over previous
//
#include <hip/hip_runtime.h>

// B=2, SQ=SKV=2048, D=1024, H=16, HD=64. Inputs fp32, output fp32.
// r14: mf=4 @1blk/CU regressed (77us, 1 wave/SIMD no overlap). r15: back to
// r10 attn geometry (512 blk, 4 waves x 32 q) but P NEVER touches LDS:
// permlane32/16_swap pairs redistribute packed exp2(P) into PV A-frags
// in-register. LDS 50KB->32KB, launch_bounds(256,3) -> ~12 waves/CU.
#define DIM   1024
#define NHEAD 16
#define HDIM  64
#define BATCH 2
#define SEQ   2048
#define MTOT  4096   // B*SQ

typedef unsigned short u16;
typedef unsigned int   u32;
typedef __attribute__((ext_vector_type(8))) short bf16x8;   // 8 bf16 = 4 VGPRs
typedef __attribute__((ext_vector_type(4))) float f32x4;
typedef __attribute__((ext_vector_type(4))) u32   u32x4;

#define QSCALE 0.18033688011112042f   // 0.125 * log2(e)
#define EXP2F(x) __builtin_amdgcn_exp2f(x)
#define SWAP32(a, b) asm volatile("v_permlane32_swap_b32 %0, %1" : "+v"(a), "+v"(b))
#define SWAP16(a, b) asm volatile("v_permlane16_swap_b32 %0, %1" : "+v"(a), "+v"(b))

__device__ __forceinline__ void gload_lds16(const void* g, void* l) {
  __builtin_amdgcn_global_load_lds((const __attribute__((address_space(1))) void*)g,
                                   (__attribute__((address_space(3))) void*)l, 16, 0, 0);
}

__device__ __forceinline__ u16 f32_to_bf16(float f) {
  union { float f; u32 u; } v; v.f = f;
  u32 r = v.u + 0x7fffu + ((v.u >> 16) & 1u);   // RNE (v_cvt_pk_bf16_f32 is NOT RNE - r12)
  return (u16)(r >> 16);
}

__device__ __forceinline__ u32 pack_bf16(float a, float b) {
  return (u32)f32_to_bf16(a) | ((u32)f32_to_bf16(b) << 16);
}

// ---------------------------------------------------------------------------
// fp32 -> bf16 for all 7 tensors (3 inputs + 4 weights), manual RNE.
// ---------------------------------------------------------------------------
struct CvtArgs {
  const float* s[7];
  u16*         d[7];
  int          n8[7];
};

__global__ __launch_bounds__(256) void cvt_all(CvtArgs a) {
  const int z = blockIdx.z;
  const float* s = a.s[z];
  u16* d = a.d[z];
  const int n8 = a.n8[z];
  const int stride = gridDim.x * blockDim.x;
  for (int i = blockIdx.x * blockDim.x + threadIdx.x; i < n8; i += stride) {
    float4 x = ((const float4*)s)[2 * i], y = ((const float4*)s)[2 * i + 1];
    u32x4 o;
    o[0] = pack_bf16(x.x, x.y); o[1] = pack_bf16(x.z, x.w);
    o[2] = pack_bf16(y.x, y.y); o[3] = pack_bf16(y.z, y.w);
    *(u32x4*)&d[(size_t)i * 8] = o;
  }
}

// ---------------------------------------------------------------------------
// bf16 GEMM body (r11-proven): tile (32*MF) x 128, BK=64, 4 waves (2x2),
// all-gload_lds staging + both-sides XOR swizzle.
// ---------------------------------------------------------------------------
template<int MF, bool OUTF32, bool BIAS_ROW>
__device__ __forceinline__ void gemm_body(
    const u16* __restrict__ X, const u16* __restrict__ W,
    const float* __restrict__ bias, void* __restrict__ Cv, int ldc, float scale,
    int m0, int n0)
{
  __shared__ __align__(16) u16 ldsA[32 * 4 * 64];
  __shared__ __align__(16) u16 ldsB[128 * 64];
  const int tid  = threadIdx.x;
  const int lane = tid & 63;
  const int wid  = tid >> 6;
  const int wr   = wid >> 1, wc = wid & 1;
  const int srow = tid >> 3;
  const int scs  = tid & 7;

  f32x4 acc[MF][4];
#pragma unroll
  for (int mf = 0; mf < MF; ++mf)
#pragma unroll
    for (int nf = 0; nf < 4; ++nf)
#pragma unroll
      for (int r = 0; r < 4; ++r) acc[mf][nf][r] = 0.f;

  for (int kt = 0; kt < DIM; kt += 64) {
    __syncthreads();
#pragma unroll
    for (int call = 0; call < MF; ++call) {
      int row = call * 32 + srow;
      int lc  = scs ^ (row & 7);
      gload_lds16(X + (size_t)(m0 + row) * DIM + kt + lc * 8,
                  &ldsA[(row * 8 + scs) * 8]);
    }
#pragma unroll
    for (int call = 0; call < 4; ++call) {
      int row = call * 32 + srow;
      int lc  = scs ^ (row & 7);
      gload_lds16(W + (size_t)(n0 + row) * DIM + kt + lc * 8,
                  &ldsB[(row * 8 + scs) * 8]);
    }
    __syncthreads();
#pragma unroll
    for (int ks = 0; ks < 2; ++ks) {
      bf16x8 af[MF], bfr[4];
#pragma unroll
      for (int mf = 0; mf < MF; ++mf) {
        int row = wr * (16 * MF) + mf * 16 + (lane & 15);
        int ch  = (ks * 4 + (lane >> 4)) ^ (row & 7);
        af[mf] = *(const bf16x8*)&ldsA[row * 64 + ch * 8];
      }
#pragma unroll
      for (int nf = 0; nf < 4; ++nf) {
        int row = wc * 64 + nf * 16 + (lane & 15);
        int ch  = (ks * 4 + (lane >> 4)) ^ (row & 7);
        bfr[nf] = *(const bf16x8*)&ldsB[row * 64 + ch * 8];
      }
#pragma unroll
      for (int mf = 0; mf < MF; ++mf)
#pragma unroll
        for (int nf = 0; nf < 4; ++nf)
          acc[mf][nf] = __builtin_amdgcn_mfma_f32_16x16x32_bf16(
              af[mf], bfr[nf], acc[mf][nf], 0, 0, 0);
    }
  }
#pragma unroll
  for (int nf = 0; nf < 4; ++nf) {
    int col = n0 + wc * 64 + nf * 16 + (lane & 15);
    float bcol = BIAS_ROW ? 0.f : bias[col];
#pragma unroll
    for (int mf = 0; mf < MF; ++mf) {
      int rbase = m0 + wr * (16 * MF) + mf * 16 + ((lane >> 4) << 2);
#pragma unroll
      for (int r = 0; r < 4; ++r) {
        float bv = BIAS_ROW ? bias[rbase + r] : bcol;
        float v = (acc[mf][nf][r] + bv) * scale;
        if (OUTF32) ((float*)Cv)[(size_t)(rbase + r) * ldc + col] = v;
        else        ((u16*)Cv)[(size_t)(rbase + r) * ldc + col] = f32_to_bf16(v);
      }
    }
  }
}

// Fused projections, 1D grid 768, XCD-chunked: z=0 Q, z=1 K, z=2 V^T.
__global__ __launch_bounds__(256, 2) void gemm_proj_kernel(
    const u16* __restrict__ q, const u16* __restrict__ k, const u16* __restrict__ v,
    const u16* __restrict__ wq, const u16* __restrict__ wk, const u16* __restrict__ wv,
    const float* __restrict__ bq, const float* __restrict__ bk, const float* __restrict__ bv,
    u16* __restrict__ oq, u16* __restrict__ ok, u16* __restrict__ ovt)
{
  const int bid = blockIdx.x;
  const int wk_ = (bid & 7) * 96 + (bid >> 3);   // 768 = 8 XCD x 96, bijective
  const int z = wk_ >> 8, rem = wk_ & 255;
  const int ty = rem >> 3, tx = rem & 7;
  if (z == 0)
    gemm_body<4, false, false>(q, wq, bq, oq, DIM, QSCALE, ty * 128, tx * 128);
  else if (z == 1)
    gemm_body<4, false, false>(k, wk, bk, ok, DIM, 1.0f, ty * 128, tx * 128);
  else
    gemm_body<4, false, true>(wv, v, bv, ovt, MTOT, 1.0f, tx * 128, ty * 128);
}

// O projection: 64x128 tile, 1D grid 512, XCD-chunked.
__global__ __launch_bounds__(256, 2) void gemm_o_kernel(
    const u16* __restrict__ x, const u16* __restrict__ w,
    const float* __restrict__ b, float* __restrict__ c)
{
  const int bid = blockIdx.x;
  const int wk_ = (bid & 7) * 64 + (bid >> 3);   // 512 = 8 x 64, bijective
  const int ty = wk_ >> 3, tx = wk_ & 7;
  gemm_body<2, true, false>(x, w, b, c, DIM, 1.0f, ty * 64, tx * 128);
}

// ---------------------------------------------------------------------------
// Flash attention r15: r10 geometry (512 blk, 4 waves x 32 q, dbuf K/V) but
// P stays in registers: after swapped QK^T, lane c+16g holds
// P[kv=16nvk+4g+r][q=16mf+c]; pack exp2 pairs into W[nvk][mf][pk], then
// (SWAP32; SWAP16) on (W[2ks], W[2ks+1]) yields PV A-frag words directly.
// LDS = 32KB (K/V dbuf only), launch_bounds(256,3).
// ---------------------------------------------------------------------------
__global__ __launch_bounds__(256, 3) void attn_kernel(
    const u16* __restrict__ Qm, const u16* __restrict__ Km,
    const u16* __restrict__ Vt, u16* __restrict__ Cm)
{
  __shared__ __align__(16) u16 Kl[2][64 * 64];
  __shared__ __align__(16) u16 Vl[2][64 * 64];

  const int tid = threadIdx.x, lane = tid & 63, wid = tid >> 6;
  const int c = lane & 15, g = lane >> 4;
  const int wkid = (blockIdx.x & 7) * 64 + (blockIdx.x >> 3);   // XCD-chunked
  const int qt = wkid & 15;
  const int bh = wkid >> 4;
  const int b = bh >> 4, h = bh & 15;
  const size_t hb = (size_t)h * HDIM;
  const int q0 = qt * 128 + wid * 32;
  const u16* Qh = Qm + ((size_t)b * SEQ + q0) * DIM + hb;
  const u16* Kh = Km + (size_t)b * SEQ * DIM + hb;
  const u16* Vh = Vt + (size_t)(h * HDIM) * MTOT + (size_t)b * SEQ;

  bf16x8 qf[2][2];
#pragma unroll
  for (int mf = 0; mf < 2; ++mf)
#pragma unroll
    for (int ks = 0; ks < 2; ++ks)
      qf[mf][ks] = *(const bf16x8*)(Qh + (size_t)(16 * mf + c) * DIM + ks * 32 + g * 8);

  bf16x8 ones;
#pragma unroll
  for (int j = 0; j < 8; ++j) ((short*)&ones)[j] = (short)0x3F80;   // bf16 1.0

  f32x4 oacc[2][4], lacc[2];
#pragma unroll
  for (int mf = 0; mf < 2; ++mf) {
#pragma unroll
    for (int nd = 0; nd < 4; ++nd)
#pragma unroll
      for (int r = 0; r < 4; ++r) oacc[mf][nd][r] = 0.f;
#pragma unroll
    for (int r = 0; r < 4; ++r) lacc[mf][r] = 0.f;
  }

  const int srow = tid >> 3, scs = tid & 7;

#define STAGE(T, BUF)                                                          \
  {                                                                            \
    const int kvs = (T) * 64;                                                  \
    _Pragma("unroll")                                                          \
    for (int call = 0; call < 2; ++call) {                                     \
      int row = call * 32 + srow;                                              \
      int lc  = scs ^ (row & 7);                                               \
      gload_lds16(Kh + (size_t)(kvs + row) * DIM + lc * 8,                     \
                  &Kl[BUF][(row * 8 + scs) * 8]);                              \
      gload_lds16(Vh + (size_t)row * MTOT + kvs + lc * 8,                      \
                  &Vl[BUF][(row * 8 + scs) * 8]);                              \
    }                                                                          \
  }

  STAGE(0, 0);

  for (int t = 0; t < 32; ++t) {
    const int cur = t & 1;
    if (t < 31) {
      STAGE(t + 1, cur ^ 1);
      asm volatile("s_waitcnt vmcnt(4)" ::: "memory");
    } else {
      asm volatile("s_waitcnt vmcnt(0)" ::: "memory");
    }
    __builtin_amdgcn_sched_barrier(0);
    __builtin_amdgcn_s_barrier();          // buf[cur] staged & visible
    __builtin_amdgcn_sched_barrier(0);

    // ---- QK^T swapped: sacc[nvk][mf] = K-tile x Q, D[kv][q] ----
    f32x4 sacc[4][2];
#pragma unroll
    for (int nvk = 0; nvk < 4; ++nvk)
#pragma unroll
      for (int mf = 0; mf < 2; ++mf)
#pragma unroll
        for (int r = 0; r < 4; ++r) sacc[nvk][mf][r] = 0.f;
#pragma unroll
    for (int ks = 0; ks < 2; ++ks) {
      bf16x8 kf[4];
#pragma unroll
      for (int nvk = 0; nvk < 4; ++nvk) {
        int row = nvk * 16 + c;
        int ch  = (ks * 4 + g) ^ (row & 7);
        kf[nvk] = *(const bf16x8*)&Kl[cur][row * 64 + ch * 8];
      }
#pragma unroll
      for (int nvk = 0; nvk < 4; ++nvk)
#pragma unroll
        for (int mf = 0; mf < 2; ++mf)
          sacc[nvk][mf] = __builtin_amdgcn_mfma_f32_16x16x32_bf16(
              kf[nvk], qf[mf][ks], sacc[nvk][mf], 0, 0, 0);
    }

    // ---- p = exp2(s), packed (manual RNE) into W[nvk][mf][pk] ----
    u32 W[4][2][2];
#pragma unroll
    for (int nvk = 0; nvk < 4; ++nvk)
#pragma unroll
      for (int mf = 0; mf < 2; ++mf) {
        W[nvk][mf][0] = pack_bf16(EXP2F(sacc[nvk][mf][0]), EXP2F(sacc[nvk][mf][1]));
        W[nvk][mf][1] = pack_bf16(EXP2F(sacc[nvk][mf][2]), EXP2F(sacc[nvk][mf][3]));
      }

    // ---- PV with in-register P: permlane swaps build A-frags ----
#pragma unroll
    for (int ks = 0; ks < 2; ++ks) {
      bf16x8 vfr[4];
#pragma unroll
      for (int nd = 0; nd < 4; ++nd) {
        int row = nd * 16 + c;             // d row of V^T tile
        int ch  = (ks * 4 + g) ^ (row & 7);
        vfr[nd] = *(const bf16x8*)&Vl[cur][row * 64 + ch * 8];
      }
#pragma unroll
      for (int mf = 0; mf < 2; ++mf) {
        u32 a0 = W[2 * ks][mf][0], b0 = W[2 * ks + 1][mf][0];
        u32 a1 = W[2 * ks][mf][1], b1 = W[2 * ks + 1][mf][1];
        SWAP32(a0, b0); SWAP16(a0, b0);    // a0 -> word0, b0 -> word2
        SWAP32(a1, b1); SWAP16(a1, b1);    // a1 -> word1, b1 -> word3
        u32x4 pw4; pw4[0] = a0; pw4[1] = a1; pw4[2] = b0; pw4[3] = b1;
        bf16x8 pa = __builtin_bit_cast(bf16x8, pw4);
        lacc[mf] = __builtin_amdgcn_mfma_f32_16x16x32_bf16(
            pa, ones, lacc[mf], 0, 0, 0);
#pragma unroll
        for (int nd = 0; nd < 4; ++nd)
          oacc[mf][nd] = __builtin_amdgcn_mfma_f32_16x16x32_bf16(
              pa, vfr[nd], oacc[mf][nd], 0, 0, 0);
      }
    }

    __builtin_amdgcn_sched_barrier(0);
    __builtin_amdgcn_s_barrier();          // all waves done with buf[cur]
  }
#undef STAGE

  // epilogue: q = q0 + 16mf + 4g + r, d = 16nd + c
#pragma unroll
  for (int mf = 0; mf < 2; ++mf)
#pragma unroll
    for (int nd = 0; nd < 4; ++nd)
#pragma unroll
      for (int r = 0; r < 4; ++r) {
        int q = q0 + 16 * mf + 4 * g + r;
        float v = oacc[mf][nd][r] / lacc[mf][r];
        Cm[((size_t)b * SEQ + q) * DIM + hb + nd * 16 + c] = f32_to_bf16(v);
      }
}

// ---------------------------------------------------------------------------
extern "C" void kernel_launch(void* const* d_in, const int* in_sizes, int n_in,
                              void* d_out, int out_size, void* d_ws, size_t ws_size,
                              hipStream_t stream)
{
  const float* query = (const float*)d_in[0];
  const float* key   = (const float*)d_in[1];
  const float* value = (const float*)d_in[2];
  const float* Wq = (const float*)d_in[3];  const float* bq = (const float*)d_in[4];
  const float* Wk = (const float*)d_in[5];  const float* bk = (const float*)d_in[6];
  const float* Wv = (const float*)d_in[7];  const float* bv = (const float*)d_in[8];
  const float* Wo = (const float*)d_in[9];  const float* bo = (const float*)d_in[10];
  float* out = (float*)d_out;

  const size_t NQKV = (size_t)MTOT * DIM;
  const size_t NW   = (size_t)DIM * DIM;
  u16* base = (u16*)d_ws;
  u16* Qb  = base;                 // [4096,1024] (pre-scaled by QSCALE)
  u16* Kb  = Qb + NQKV;
  u16* Vtb = Kb + NQKV;            // [1024,4096] V^T
  u16* Cb  = Vtb + NQKV;
  u16* qc  = Cb + NQKV;
  u16* kc  = qc + NQKV;
  u16* vc  = kc + NQKV;
  u16* wqc = vc + NQKV;
  u16* wkc = wqc + NW;
  u16* wvc = wkc + NW;
  u16* woc = wvc + NW;

  CvtArgs ca;
  ca.s[0] = query; ca.s[1] = key; ca.s[2] = value;
  ca.s[3] = Wq; ca.s[4] = Wk; ca.s[5] = Wv; ca.s[6] = Wo;
  ca.d[0] = qc; ca.d[1] = kc; ca.d[2] = vc;
  ca.d[3] = wqc; ca.d[4] = wkc; ca.d[5] = wvc; ca.d[6] = woc;
  for (int i = 0; i < 3; ++i) ca.n8[i] = (int)(NQKV / 8);
  for (int i = 3; i < 7; ++i) ca.n8[i] = (int)(NW / 8);
  cvt_all<<<dim3(256, 1, 7), 256, 0, stream>>>(ca);

  dim3 blk(256);
  gemm_proj_kernel<<<768, blk, 0, stream>>>(
      qc, kc, vc, wqc, wkc, wvc, bq, bk, bv, Qb, Kb, Vtb);
  attn_kernel<<<512, blk, 0, stream>>>(Qb, Kb, Vtb, Cb);
  gemm_o_kernel<<<512, blk, 0, stream>>>(Cb, woc, bo, out);
}

// Round 16
// 120.890 us; speedup vs baseline: 1.1814x; 1.0386x over previous
//
#include <hip/hip_runtime.h>

// B=2, SQ=SKV=2048, D=1024, H=16, HD=64. Inputs fp32, output fp32.
// r15: 125.5us (attn 59.4: P-in-register via permlane proven, conflicts 0,
// but grid=512 caps occupancy at 2 blk/CU -> sync overhead dominates).
// r16: attn KVBLK=128 (16 iters, half the barriers/vmcnt waits; VGPR growth
// free since grid-limited) + setprio(1) around compute. Proj/cvt/o unchanged.
#define DIM   1024
#define NHEAD 16
#define HDIM  64
#define BATCH 2
#define SEQ   2048
#define MTOT  4096   // B*SQ

typedef unsigned short u16;
typedef unsigned int   u32;
typedef __attribute__((ext_vector_type(8))) short bf16x8;   // 8 bf16 = 4 VGPRs
typedef __attribute__((ext_vector_type(4))) float f32x4;
typedef __attribute__((ext_vector_type(4))) u32   u32x4;

#define QSCALE 0.18033688011112042f   // 0.125 * log2(e)
#define EXP2F(x) __builtin_amdgcn_exp2f(x)
#define SWAP32(a, b) asm volatile("v_permlane32_swap_b32 %0, %1" : "+v"(a), "+v"(b))
#define SWAP16(a, b) asm volatile("v_permlane16_swap_b32 %0, %1" : "+v"(a), "+v"(b))

__device__ __forceinline__ void gload_lds16(const void* g, void* l) {
  __builtin_amdgcn_global_load_lds((const __attribute__((address_space(1))) void*)g,
                                   (__attribute__((address_space(3))) void*)l, 16, 0, 0);
}

__device__ __forceinline__ u16 f32_to_bf16(float f) {
  union { float f; u32 u; } v; v.f = f;
  u32 r = v.u + 0x7fffu + ((v.u >> 16) & 1u);   // RNE (v_cvt_pk_bf16_f32 is NOT RNE - r12)
  return (u16)(r >> 16);
}

__device__ __forceinline__ u32 pack_bf16(float a, float b) {
  return (u32)f32_to_bf16(a) | ((u32)f32_to_bf16(b) << 16);
}

// ---------------------------------------------------------------------------
// fp32 -> bf16 for all 7 tensors (3 inputs + 4 weights), manual RNE.
// ---------------------------------------------------------------------------
struct CvtArgs {
  const float* s[7];
  u16*         d[7];
  int          n8[7];
};

__global__ __launch_bounds__(256) void cvt_all(CvtArgs a) {
  const int z = blockIdx.z;
  const float* s = a.s[z];
  u16* d = a.d[z];
  const int n8 = a.n8[z];
  const int stride = gridDim.x * blockDim.x;
  for (int i = blockIdx.x * blockDim.x + threadIdx.x; i < n8; i += stride) {
    float4 x = ((const float4*)s)[2 * i], y = ((const float4*)s)[2 * i + 1];
    u32x4 o;
    o[0] = pack_bf16(x.x, x.y); o[1] = pack_bf16(x.z, x.w);
    o[2] = pack_bf16(y.x, y.y); o[3] = pack_bf16(y.z, y.w);
    *(u32x4*)&d[(size_t)i * 8] = o;
  }
}

// ---------------------------------------------------------------------------
// bf16 GEMM body (proven): tile (32*MF) x 128, BK=64, 4 waves (2x2),
// all-gload_lds staging + both-sides XOR swizzle.
// ---------------------------------------------------------------------------
template<int MF, bool OUTF32, bool BIAS_ROW>
__device__ __forceinline__ void gemm_body(
    const u16* __restrict__ X, const u16* __restrict__ W,
    const float* __restrict__ bias, void* __restrict__ Cv, int ldc, float scale,
    int m0, int n0)
{
  __shared__ __align__(16) u16 ldsA[32 * 4 * 64];
  __shared__ __align__(16) u16 ldsB[128 * 64];
  const int tid  = threadIdx.x;
  const int lane = tid & 63;
  const int wid  = tid >> 6;
  const int wr   = wid >> 1, wc = wid & 1;
  const int srow = tid >> 3;
  const int scs  = tid & 7;

  f32x4 acc[MF][4];
#pragma unroll
  for (int mf = 0; mf < MF; ++mf)
#pragma unroll
    for (int nf = 0; nf < 4; ++nf)
#pragma unroll
      for (int r = 0; r < 4; ++r) acc[mf][nf][r] = 0.f;

  for (int kt = 0; kt < DIM; kt += 64) {
    __syncthreads();
#pragma unroll
    for (int call = 0; call < MF; ++call) {
      int row = call * 32 + srow;
      int lc  = scs ^ (row & 7);
      gload_lds16(X + (size_t)(m0 + row) * DIM + kt + lc * 8,
                  &ldsA[(row * 8 + scs) * 8]);
    }
#pragma unroll
    for (int call = 0; call < 4; ++call) {
      int row = call * 32 + srow;
      int lc  = scs ^ (row & 7);
      gload_lds16(W + (size_t)(n0 + row) * DIM + kt + lc * 8,
                  &ldsB[(row * 8 + scs) * 8]);
    }
    __syncthreads();
#pragma unroll
    for (int ks = 0; ks < 2; ++ks) {
      bf16x8 af[MF], bfr[4];
#pragma unroll
      for (int mf = 0; mf < MF; ++mf) {
        int row = wr * (16 * MF) + mf * 16 + (lane & 15);
        int ch  = (ks * 4 + (lane >> 4)) ^ (row & 7);
        af[mf] = *(const bf16x8*)&ldsA[row * 64 + ch * 8];
      }
#pragma unroll
      for (int nf = 0; nf < 4; ++nf) {
        int row = wc * 64 + nf * 16 + (lane & 15);
        int ch  = (ks * 4 + (lane >> 4)) ^ (row & 7);
        bfr[nf] = *(const bf16x8*)&ldsB[row * 64 + ch * 8];
      }
#pragma unroll
      for (int mf = 0; mf < MF; ++mf)
#pragma unroll
        for (int nf = 0; nf < 4; ++nf)
          acc[mf][nf] = __builtin_amdgcn_mfma_f32_16x16x32_bf16(
              af[mf], bfr[nf], acc[mf][nf], 0, 0, 0);
    }
  }
#pragma unroll
  for (int nf = 0; nf < 4; ++nf) {
    int col = n0 + wc * 64 + nf * 16 + (lane & 15);
    float bcol = BIAS_ROW ? 0.f : bias[col];
#pragma unroll
    for (int mf = 0; mf < MF; ++mf) {
      int rbase = m0 + wr * (16 * MF) + mf * 16 + ((lane >> 4) << 2);
#pragma unroll
      for (int r = 0; r < 4; ++r) {
        float bv = BIAS_ROW ? bias[rbase + r] : bcol;
        float v = (acc[mf][nf][r] + bv) * scale;
        if (OUTF32) ((float*)Cv)[(size_t)(rbase + r) * ldc + col] = v;
        else        ((u16*)Cv)[(size_t)(rbase + r) * ldc + col] = f32_to_bf16(v);
      }
    }
  }
}

// Fused projections, 1D grid 768, XCD-chunked: z=0 Q, z=1 K, z=2 V^T.
__global__ __launch_bounds__(256, 2) void gemm_proj_kernel(
    const u16* __restrict__ q, const u16* __restrict__ k, const u16* __restrict__ v,
    const u16* __restrict__ wq, const u16* __restrict__ wk, const u16* __restrict__ wv,
    const float* __restrict__ bq, const float* __restrict__ bk, const float* __restrict__ bv,
    u16* __restrict__ oq, u16* __restrict__ ok, u16* __restrict__ ovt)
{
  const int bid = blockIdx.x;
  const int wk_ = (bid & 7) * 96 + (bid >> 3);   // 768 = 8 XCD x 96, bijective
  const int z = wk_ >> 8, rem = wk_ & 255;
  const int ty = rem >> 3, tx = rem & 7;
  if (z == 0)
    gemm_body<4, false, false>(q, wq, bq, oq, DIM, QSCALE, ty * 128, tx * 128);
  else if (z == 1)
    gemm_body<4, false, false>(k, wk, bk, ok, DIM, 1.0f, ty * 128, tx * 128);
  else
    gemm_body<4, false, true>(wv, v, bv, ovt, MTOT, 1.0f, tx * 128, ty * 128);
}

// O projection: 64x128 tile, 1D grid 512, XCD-chunked.
__global__ __launch_bounds__(256, 2) void gemm_o_kernel(
    const u16* __restrict__ x, const u16* __restrict__ w,
    const float* __restrict__ b, float* __restrict__ c)
{
  const int bid = blockIdx.x;
  const int wk_ = (bid & 7) * 64 + (bid >> 3);   // 512 = 8 x 64, bijective
  const int ty = wk_ >> 3, tx = wk_ & 7;
  gemm_body<2, true, false>(x, w, b, c, DIM, 1.0f, ty * 64, tx * 128);
}

// ---------------------------------------------------------------------------
// Flash attention r16: 512 blk, 4 waves x 32 q, KVBLK=128 (16 iterations).
// K[128kv][64d] swizzle (row&7); Vt[64d][128kv] 16-chunk swizzle (row&15).
// Swapped QK^T (streamed per nvk, sacc[2] live) -> exp2 -> packed W[8][2][2]
// -> permlane-swap PV A-frags (P never in LDS). setprio(1) around compute.
// LDS = 64KB (K/V dbuf), grid-limited 2 blk/CU so VGPR growth is free.
// ---------------------------------------------------------------------------
__global__ __launch_bounds__(256, 2) void attn_kernel(
    const u16* __restrict__ Qm, const u16* __restrict__ Km,
    const u16* __restrict__ Vt, u16* __restrict__ Cm)
{
  __shared__ __align__(16) u16 Kl[2][128 * 64];
  __shared__ __align__(16) u16 Vl[2][64 * 128];

  const int tid = threadIdx.x, lane = tid & 63, wid = tid >> 6;
  const int c = lane & 15, g = lane >> 4;
  const int wkid = (blockIdx.x & 7) * 64 + (blockIdx.x >> 3);   // XCD-chunked
  const int qt = wkid & 15;
  const int bh = wkid >> 4;
  const int b = bh >> 4, h = bh & 15;
  const size_t hb = (size_t)h * HDIM;
  const int q0 = qt * 128 + wid * 32;
  const u16* Qh = Qm + ((size_t)b * SEQ + q0) * DIM + hb;
  const u16* Kh = Km + (size_t)b * SEQ * DIM + hb;
  const u16* Vh = Vt + (size_t)(h * HDIM) * MTOT + (size_t)b * SEQ;

  bf16x8 qf[2][2];
#pragma unroll
  for (int mf = 0; mf < 2; ++mf)
#pragma unroll
    for (int ks = 0; ks < 2; ++ks)
      qf[mf][ks] = *(const bf16x8*)(Qh + (size_t)(16 * mf + c) * DIM + ks * 32 + g * 8);

  bf16x8 ones;
#pragma unroll
  for (int j = 0; j < 8; ++j) ((short*)&ones)[j] = (short)0x3F80;   // bf16 1.0

  f32x4 oacc[2][4], lacc[2];
#pragma unroll
  for (int mf = 0; mf < 2; ++mf) {
#pragma unroll
    for (int nd = 0; nd < 4; ++nd)
#pragma unroll
      for (int r = 0; r < 4; ++r) oacc[mf][nd][r] = 0.f;
#pragma unroll
    for (int r = 0; r < 4; ++r) lacc[mf][r] = 0.f;
  }

  const int srow = tid >> 3, scs = tid & 7;      // K staging (8 chunks/row)
  const int srow2 = tid >> 4, scs2 = tid & 15;   // V staging (16 chunks/row)

  // stage one 128-kv tile: K 4 calls (32 rows each), V 4 calls (16 rows each)
#define STAGE(T, BUF)                                                          \
  {                                                                            \
    const int kvs = (T) * 128;                                                 \
    _Pragma("unroll")                                                          \
    for (int call = 0; call < 4; ++call) {                                     \
      int row = call * 32 + srow;                                              \
      int lc  = scs ^ (row & 7);                                               \
      gload_lds16(Kh + (size_t)(kvs + row) * DIM + lc * 8,                     \
                  &Kl[BUF][(row * 8 + scs) * 8]);                              \
    }                                                                          \
    _Pragma("unroll")                                                          \
    for (int call = 0; call < 4; ++call) {                                     \
      int row = call * 16 + srow2;                                             \
      int lc  = scs2 ^ (row & 15);                                             \
      gload_lds16(Vh + (size_t)row * MTOT + kvs + lc * 8,                      \
                  &Vl[BUF][(row * 16 + scs2) * 8]);                            \
    }                                                                          \
  }

  STAGE(0, 0);

  for (int t = 0; t < 16; ++t) {
    const int cur = t & 1;
    if (t < 15) {
      STAGE(t + 1, cur ^ 1);
      asm volatile("s_waitcnt vmcnt(8)" ::: "memory");
    } else {
      asm volatile("s_waitcnt vmcnt(0)" ::: "memory");
    }
    __builtin_amdgcn_sched_barrier(0);
    __builtin_amdgcn_s_barrier();          // buf[cur] staged & visible
    __builtin_amdgcn_sched_barrier(0);
    __builtin_amdgcn_s_setprio(1);

    // ---- QK^T swapped, streamed per nvk: P[kv=16nvk+4g+r][q=16mf+c] ----
    u32 W[8][2][2];
#pragma unroll
    for (int nvk = 0; nvk < 8; ++nvk) {
      int row = nvk * 16 + c;              // kv row in 128-tile
      f32x4 sacc[2];
#pragma unroll
      for (int mf = 0; mf < 2; ++mf)
#pragma unroll
        for (int r = 0; r < 4; ++r) sacc[mf][r] = 0.f;
#pragma unroll
      for (int ks = 0; ks < 2; ++ks) {
        int ch = (ks * 4 + g) ^ (row & 7);
        bf16x8 kf = *(const bf16x8*)&Kl[cur][row * 64 + ch * 8];
#pragma unroll
        for (int mf = 0; mf < 2; ++mf)
          sacc[mf] = __builtin_amdgcn_mfma_f32_16x16x32_bf16(
              kf, qf[mf][ks], sacc[mf], 0, 0, 0);
      }
#pragma unroll
      for (int mf = 0; mf < 2; ++mf) {
        W[nvk][mf][0] = pack_bf16(EXP2F(sacc[mf][0]), EXP2F(sacc[mf][1]));
        W[nvk][mf][1] = pack_bf16(EXP2F(sacc[mf][2]), EXP2F(sacc[mf][3]));
      }
    }

    // ---- PV with in-register P: ks 0..3 over kv=128 ----
#pragma unroll
    for (int ks = 0; ks < 4; ++ks) {
      bf16x8 vfr[4];
#pragma unroll
      for (int nd = 0; nd < 4; ++nd) {
        int row = nd * 16 + c;             // d row of V^T tile
        int ch  = (ks * 4 + g) ^ (row & 15);
        vfr[nd] = *(const bf16x8*)&Vl[cur][row * 128 + ch * 8];
      }
#pragma unroll
      for (int mf = 0; mf < 2; ++mf) {
        u32 a0 = W[2 * ks][mf][0], b0 = W[2 * ks + 1][mf][0];
        u32 a1 = W[2 * ks][mf][1], b1 = W[2 * ks + 1][mf][1];
        SWAP32(a0, b0); SWAP16(a0, b0);
        SWAP32(a1, b1); SWAP16(a1, b1);
        u32x4 pw4; pw4[0] = a0; pw4[1] = a1; pw4[2] = b0; pw4[3] = b1;
        bf16x8 pa = __builtin_bit_cast(bf16x8, pw4);
        lacc[mf] = __builtin_amdgcn_mfma_f32_16x16x32_bf16(
            pa, ones, lacc[mf], 0, 0, 0);
#pragma unroll
        for (int nd = 0; nd < 4; ++nd)
          oacc[mf][nd] = __builtin_amdgcn_mfma_f32_16x16x32_bf16(
              pa, vfr[nd], oacc[mf][nd], 0, 0, 0);
      }
    }

    __builtin_amdgcn_s_setprio(0);
    __builtin_amdgcn_sched_barrier(0);
    __builtin_amdgcn_s_barrier();          // all waves done with buf[cur]
  }
#undef STAGE

  // epilogue: q = q0 + 16mf + 4g + r, d = 16nd + c
#pragma unroll
  for (int mf = 0; mf < 2; ++mf)
#pragma unroll
    for (int nd = 0; nd < 4; ++nd)
#pragma unroll
      for (int r = 0; r < 4; ++r) {
        int q = q0 + 16 * mf + 4 * g + r;
        float v = oacc[mf][nd][r] / lacc[mf][r];
        Cm[((size_t)b * SEQ + q) * DIM + hb + nd * 16 + c] = f32_to_bf16(v);
      }
}

// ---------------------------------------------------------------------------
extern "C" void kernel_launch(void* const* d_in, const int* in_sizes, int n_in,
                              void* d_out, int out_size, void* d_ws, size_t ws_size,
                              hipStream_t stream)
{
  const float* query = (const float*)d_in[0];
  const float* key   = (const float*)d_in[1];
  const float* value = (const float*)d_in[2];
  const float* Wq = (const float*)d_in[3];  const float* bq = (const float*)d_in[4];
  const float* Wk = (const float*)d_in[5];  const float* bk = (const float*)d_in[6];
  const float* Wv = (const float*)d_in[7];  const float* bv = (const float*)d_in[8];
  const float* Wo = (const float*)d_in[9];  const float* bo = (const float*)d_in[10];
  float* out = (float*)d_out;

  const size_t NQKV = (size_t)MTOT * DIM;
  const size_t NW   = (size_t)DIM * DIM;
  u16* base = (u16*)d_ws;
  u16* Qb  = base;                 // [4096,1024] (pre-scaled by QSCALE)
  u16* Kb  = Qb + NQKV;
  u16* Vtb = Kb + NQKV;            // [1024,4096] V^T
  u16* Cb  = Vtb + NQKV;
  u16* qc  = Cb + NQKV;
  u16* kc  = qc + NQKV;
  u16* vc  = kc + NQKV;
  u16* wqc = vc + NQKV;
  u16* wkc = wqc + NW;
  u16* wvc = wkc + NW;
  u16* woc = wvc + NW;

  CvtArgs ca;
  ca.s[0] = query; ca.s[1] = key; ca.s[2] = value;
  ca.s[3] = Wq; ca.s[4] = Wk; ca.s[5] = Wv; ca.s[6] = Wo;
  ca.d[0] = qc; ca.d[1] = kc; ca.d[2] = vc;
  ca.d[3] = wqc; ca.d[4] = wkc; ca.d[5] = wvc; ca.d[6] = woc;
  for (int i = 0; i < 3; ++i) ca.n8[i] = (int)(NQKV / 8);
  for (int i = 3; i < 7; ++i) ca.n8[i] = (int)(NW / 8);
  cvt_all<<<dim3(256, 1, 7), 256, 0, stream>>>(ca);

  dim3 blk(256);
  gemm_proj_kernel<<<768, blk, 0, stream>>>(
      qc, kc, vc, wqc, wkc, wvc, bq, bk, bv, Qb, Kb, Vtb);
  attn_kernel<<<512, blk, 0, stream>>>(Qb, Kb, Vtb, Cb);
  gemm_o_kernel<<<512, blk, 0, stream>>>(Cb, woc, bo, out);
}